// Round 12
// baseline (307.983 us; speedup 1.0000x reference)
//
#include <hip/hip_runtime.h>
#include <hip/hip_bf16.h>

// NoisyActLin: y = fakequant(x) @ fakequant(W).T + bias
// x: [4,2048,2048] f32 -> M=8192, K=2048 ; W: [8192,2048] f32 -> N=8192
// out: [8192, 8192] f32
//
// GEMM R12 (= R11 with lgkmcnt(15): the lgkmcnt field is 4 bits, max 15):
// 256x256 tile, BK=64, 4 waves (2Mx2N), 128x128 per wave.
// Rationale (R10 post-mortem): every barrier-lockstep schedule serializes
// LDS-port time with MFMA time. 4 waves cut LDS frag reads/K-tile by 33%
// (131KB vs 196KB) and make per-SIMD MFMA content (2483cyc) exceed the port
// total (1536cyc) -> port hides under MFMA.
// launch_bounds(256,1): acc 256 + frags 128 regs fits the 512 unified file.
// R9/R10 wait discipline: lands-guarantee = own-wave vmcnt(0) BEFORE barrier.

using f16x8 = __attribute__((ext_vector_type(8))) _Float16;
using f32x4 = __attribute__((ext_vector_type(4))) float;

#define AS1 __attribute__((address_space(1)))
#define AS3 __attribute__((address_space(3)))

static __device__ __forceinline__ void gload_lds16(const void* g, void* l) {
    __builtin_amdgcn_global_load_lds((const AS1 void*)g, (AS3 void*)l, 16, 0, 0);
}

// ---------------- weight fake-quant: one block per row ----------------
__global__ __launch_bounds__(256) void wquant_kernel(
    const float* __restrict__ W, const float* __restrict__ lws,
    _Float16* __restrict__ Wq) {
    constexpr int K = 2048;
    const int row = blockIdx.x;
    const int t = threadIdx.x;
    const float* w = W + (size_t)row * K;

    float4 v0 = ((const float4*)w)[t * 2];
    float4 v1 = ((const float4*)w)[t * 2 + 1];
    float vals[8] = {v0.x, v0.y, v0.z, v0.w, v1.x, v1.y, v1.z, v1.w};

    float mn = vals[0], mx = vals[0];
#pragma unroll
    for (int i = 1; i < 8; ++i) {
        mn = fminf(mn, vals[i]);
        mx = fmaxf(mx, vals[i]);
    }
#pragma unroll
    for (int off = 32; off >= 1; off >>= 1) {
        mn = fminf(mn, __shfl_xor(mn, off));
        mx = fmaxf(mx, __shfl_xor(mx, off));
    }
    __shared__ float smn[4], smx[4];
    if ((t & 63) == 0) { smn[t >> 6] = mn; smx[t >> 6] = mx; }
    __syncthreads();
    mn = fminf(fminf(smn[0], smn[1]), fminf(smn[2], smn[3]));
    mx = fmaxf(fmaxf(smx[0], smx[1]), fmaxf(smx[2], smx[3]));

    const float l = lws[row];
    const float ws = exp2f(l);     // power of two -> exact
    const float rs = exp2f(-l);    // exact reciprocal
    const float qwmin = rintf(mn * rs * 2.0f) * 0.5f * ws;
    const float qwmax = rintf(mx * rs * 2.0f) * 0.5f * ws;

    f16x8 out;
#pragma unroll
    for (int i = 0; i < 8; ++i) {
        float c = fminf(fmaxf(vals[i], qwmin), qwmax);
        float qw = rintf((c - qwmin) * rs);
        out[i] = (_Float16)(qw * ws + qwmin);
    }
    *(f16x8*)&Wq[(size_t)row * K + (size_t)t * 8] = out;
}

// ---------------- activation fake-quant: elementwise ----------------
__global__ __launch_bounds__(256) void xquant_kernel(
    const float* __restrict__ X,
    const float* __restrict__ las, const float* __restrict__ laq,
    const float* __restrict__ ab, _Float16* __restrict__ Xq) {
    const float ls = las[0], lq = laq[0];
    const float s = exp2f(ls);
    const float rs = exp2f(-ls);
    const float q = exp2f(lq);
    const float zp = rintf(ab[0] * rs * 2.0f) * 0.5f * s;
    const float lo = zp;
    const float hi = (zp + q) - s;

    const size_t base = ((size_t)blockIdx.x * 256 + threadIdx.x) * 8;
    float4 v0 = *(const float4*)&X[base];
    float4 v1 = *(const float4*)&X[base + 4];
    float vals[8] = {v0.x, v0.y, v0.z, v0.w, v1.x, v1.y, v1.z, v1.w};

    f16x8 out;
#pragma unroll
    for (int i = 0; i < 8; ++i) {
        float c = fminf(fmaxf(vals[i], lo), hi);
        float qx = rintf((c - zp) * rs);
        out[i] = (_Float16)(qx * s + zp);
    }
    *(f16x8*)&Xq[base] = out;
}

// ---------------- GEMM: C[M][N] = A[M][K] * B[N][K]^T + bias ----------------
// LDS: A [db2][half2][128][64] f16 at 0 (64KB), B same at +65536 (128KB).
// 4 waves: wave (wr=wid>>1, wc=wid&1) owns C[wr*128..+128][wc*128..+128].
// Phase kt (db=kt&1), 32 phases:
//   STAGET(db^1, kt+1): 16 gload_lds/thread (256 thr x 16B x 16 = 64KB)
//   32 ds_read_b128/wave (16 ks0, 16 ks1)
//   lgkm(15) ; 64 MFMA(ks0) ; lgkm(0) ; 64 MFMA(ks1)
//   VMC(0) ; BAR   (own stage loads drained BEFORE barrier)
// WAR: stage targets tile kt-1's slots; readers drained at phase kt-1's
// lgkm(0) before that BAR. Landing: after BAR all waves' loads landed.
__global__ __launch_bounds__(256, 1) void gemm_kernel(
    const _Float16* __restrict__ A, const _Float16* __restrict__ B,
    const float* __restrict__ bias, float* __restrict__ C) {
    constexpr int N = 8192, K = 2048;
    constexpr int KT = K / 64;          // 32 K-tiles = 32 phases
    constexpr int NBN = N / 256;        // 32

    __shared__ char smem[131072];       // A: 0..64K, B: 64K..128K

    // XCD-aware swizzle (nwg = 1024, %8 == 0 -> bijective)
    const int bid = blockIdx.x;
    const int cpx = gridDim.x >> 3;
    const int swzb = (bid & 7) * cpx + (bid >> 3);
    const int bm = swzb / NBN;
    const int bn = swzb % NBN;

    const int t = threadIdx.x;
    const int lane = t & 63;
    const int wid = t >> 6;             // 0..3
    const int wr = wid >> 1;            // 0..1 (M half)
    const int wc = wid & 1;             // 0..1 (N half)
    const int l15 = lane & 15;
    const int lq = lane >> 4;

    // staging: half-tile [128 rows][64 k] f16 = 16384 B, linear LDS dest,
    // pre-swizzled global source. T2: byte ^= (row&7)<<4 (verified 0 cf).
    // 256 threads: 4 rounds per half-tile, row = r0 + 32j, col invariant.
    const int d0 = t * 16;
    const int r0 = t >> 3;
    const int c0 = (((d0 & 127) ^ ((r0 & 7) << 4)) >> 1);
    const _Float16* Agb = A + (size_t)bm * 256 * K;
    const _Float16* Bgb = B + (size_t)bn * 256 * K;

    // read-side swizzled k-col byte offsets (frag row&7 == l15&7)
    const int cp0 = (lq * 16) ^ ((l15 & 7) << 4);
    const int cp1 = cp0 ^ 64;           // second K-half (bit6 XOR)

    f32x4 acc[8][8] = {};
    f16x8 fA[8][2], fB[8][2];

#define STAGEH(GB, RO, DBS, H, KS) do {                                        \
        const _Float16* _g = (GB) + (size_t)((H) * 128) * K +                  \
                             (size_t)(KS) * 64 + c0;                           \
        char* _l = smem + (RO) + ((DBS) * 2 + (H)) * 16384 + d0;               \
        gload_lds16(_g + (size_t)(r0 +  0) * K, _l +     0);                   \
        gload_lds16(_g + (size_t)(r0 + 32) * K, _l +  4096);                   \
        gload_lds16(_g + (size_t)(r0 + 64) * K, _l +  8192);                   \
        gload_lds16(_g + (size_t)(r0 + 96) * K, _l + 12288);                   \
    } while (0)

#define STAGET(DBS, KS) do {                                                   \
        STAGEH(Agb, 0,     DBS, 0, KS);                                        \
        STAGEH(Agb, 0,     DBS, 1, KS);                                        \
        STAGEH(Bgb, 65536, DBS, 0, KS);                                        \
        STAGEH(Bgb, 65536, DBS, 1, KS);                                        \
    } while (0)

#define VMC(NN) asm volatile("s_waitcnt vmcnt(" #NN ")" ::: "memory")
#define BAR()   __builtin_amdgcn_s_barrier()
#define PRIO(P) __builtin_amdgcn_s_setprio(P)

    // ---- prologue: stage tile 0 into db0; drain BEFORE barrier ----
    STAGET(0, 0);
    VMC(0);
    BAR();

    for (int kt = 0; kt < KT; ++kt) {
        const int db = kt & 1;
        const int nx = (kt + 1 < KT) ? kt + 1 : KT - 1;

        STAGET(db ^ 1, nx);              // 16 loads for tile kt+1

        // 32 ds_read_b128 of tile kt, grouped by k-slice
        const char* _a = smem + (db * 2 + wr) * 16384 + l15 * 128;
        const char* _b = smem + 65536 + (db * 2 + wc) * 16384 + l15 * 128;
#pragma unroll
        for (int m = 0; m < 8; ++m)
            fA[m][0] = *(const f16x8*)(_a + m * 2048 + cp0);
#pragma unroll
        for (int n = 0; n < 8; ++n)
            fB[n][0] = *(const f16x8*)(_b + n * 2048 + cp0);
#pragma unroll
        for (int m = 0; m < 8; ++m)
            fA[m][1] = *(const f16x8*)(_a + m * 2048 + cp1);
#pragma unroll
        for (int n = 0; n < 8; ++n)
            fB[n][1] = *(const f16x8*)(_b + n * 2048 + cp1);

        // ks0 cluster: lgkmcnt field max is 15 (4 bits) — waits for the 16
        // ks0 reads + 1 ks1 read; 15 ks1 reads drain under the MFMAs.
        asm volatile("s_waitcnt lgkmcnt(15)" ::: "memory");
        __builtin_amdgcn_sched_barrier(0);
        PRIO(1);
#pragma unroll
        for (int m = 0; m < 8; ++m)
#pragma unroll
            for (int n = 0; n < 8; ++n)
                acc[m][n] = __builtin_amdgcn_mfma_f32_16x16x32_f16(
                    fA[m][0], fB[n][0], acc[m][n], 0, 0, 0);
        PRIO(0);

        // ks1 cluster
        asm volatile("s_waitcnt lgkmcnt(0)" ::: "memory");
        __builtin_amdgcn_sched_barrier(0);
        PRIO(1);
#pragma unroll
        for (int m = 0; m < 8; ++m)
#pragma unroll
            for (int n = 0; n < 8; ++n)
                acc[m][n] = __builtin_amdgcn_mfma_f32_16x16x32_f16(
                    fA[m][1], fB[n][1], acc[m][n], 0, 0, 0);
        PRIO(0);

        VMC(0);                          // own stage loads drained
        BAR();                           // => all waves' loads landed
    }
#undef STAGEH
#undef STAGET
#undef VMC
#undef BAR
#undef PRIO

    // ---- epilogue: C/D mapping col=lane&15, row=(lane>>4)*4+reg ----
#pragma unroll
    for (int m = 0; m < 8; ++m) {
        const int row = bm * 256 + wr * 128 + m * 16 + lq * 4;
#pragma unroll
        for (int n = 0; n < 8; ++n) {
            const int col = bn * 256 + wc * 128 + n * 16 + l15;
            const float bv = bias[col];
#pragma unroll
            for (int r = 0; r < 4; ++r) {
                C[(size_t)(row + r) * N + col] = acc[m][n][r] + bv;
            }
        }
    }
}

extern "C" void kernel_launch(void* const* d_in, const int* in_sizes, int n_in,
                              void* d_out, int out_size, void* d_ws, size_t ws_size,
                              hipStream_t stream) {
    const float* x    = (const float*)d_in[0];   // [4,2048,2048]
    const float* w    = (const float*)d_in[1];   // [8192,2048]
    const float* bias = (const float*)d_in[2];   // [8192]
    const float* las  = (const float*)d_in[3];   // log_act_s [1]
    const float* laq  = (const float*)d_in[4];   // log_act_q [1]
    const float* ab   = (const float*)d_in[5];   // act_b [1]
    const float* lws  = (const float*)d_in[6];   // log_wght_s [8192]
    float* out = (float*)d_out;

    constexpr size_t MK = (size_t)8192 * 2048;
    _Float16* xq = (_Float16*)d_ws;
    _Float16* wq = (_Float16*)((char*)d_ws + MK * sizeof(_Float16));

    xquant_kernel<<<8192, 256, 0, stream>>>(x, las, laq, ab, xq);
    wquant_kernel<<<8192, 256, 0, stream>>>(w, lws, wq);
    gemm_kernel<<<1024, 256, 0, stream>>>(xq, wq, bias, out);
}

// Round 13
// 278.306 us; speedup vs baseline: 1.1066x; 1.1066x over previous
//
#include <hip/hip_runtime.h>
#include <hip/hip_bf16.h>

// NoisyActLin: y = fakequant(x) @ fakequant(W).T + bias
// x: [4,2048,2048] f32 -> M=8192, K=2048 ; W: [8192,2048] f32 -> N=8192
// out: [8192, 8192] f32
//
// R13 = R5 GEMM (measured best: 265us, MfmaUtil 45.5, 0 bank conflicts)
// with (1) L2/L3-aware block mapping: each XCD owns a 4-row A-band (fits
// its 4MB L2); all XCDs sweep bn in lockstep so B panels are fetched from
// HBM ~once chip-wide (FETCH was 541MB vs 67MB ideal — the re-fetch tax is
// the latency the schedule couldn't hide); (2) merged quant kernel.

using f16x8 = __attribute__((ext_vector_type(8))) _Float16;
using f32x4 = __attribute__((ext_vector_type(4))) float;

#define AS1 __attribute__((address_space(1)))
#define AS3 __attribute__((address_space(3)))

static __device__ __forceinline__ void gload_lds16(const void* g, void* l) {
    __builtin_amdgcn_global_load_lds((const AS1 void*)g, (AS3 void*)l, 16, 0, 0);
}

// ---------------- fused fake-quant: x elementwise + W per-row ----------------
__global__ __launch_bounds__(256) void quant_kernel(
    const float* __restrict__ X,
    const float* __restrict__ las, const float* __restrict__ laq,
    const float* __restrict__ ab,
    const float* __restrict__ W, const float* __restrict__ lws,
    _Float16* __restrict__ Xq, _Float16* __restrict__ Wq) {
    constexpr int K = 2048;
    __shared__ float smn[4], smx[4];
    const int t = threadIdx.x;

    if (blockIdx.x < 8192) {
        // ---- activation fake-quant (elementwise) ----
        const float ls = las[0], lq = laq[0];
        const float s = exp2f(ls);
        const float rs = exp2f(-ls);
        const float q = exp2f(lq);
        const float zp = rintf(ab[0] * rs * 2.0f) * 0.5f * s;  // ACT_GUARD=2
        const float lo = zp;
        const float hi = (zp + q) - s;

        const size_t base = ((size_t)blockIdx.x * 256 + t) * 8;
        float4 v0 = *(const float4*)&X[base];
        float4 v1 = *(const float4*)&X[base + 4];
        float vals[8] = {v0.x, v0.y, v0.z, v0.w, v1.x, v1.y, v1.z, v1.w};

        f16x8 out;
#pragma unroll
        for (int i = 0; i < 8; ++i) {
            float c = fminf(fmaxf(vals[i], lo), hi);
            float qx = rintf((c - zp) * rs);
            out[i] = (_Float16)(qx * s + zp);
        }
        *(f16x8*)&Xq[base] = out;
    } else {
        // ---- weight fake-quant (per-row amin/amax) ----
        const int row = blockIdx.x - 8192;
        const float* w = W + (size_t)row * K;

        float4 v0 = ((const float4*)w)[t * 2];
        float4 v1 = ((const float4*)w)[t * 2 + 1];
        float vals[8] = {v0.x, v0.y, v0.z, v0.w, v1.x, v1.y, v1.z, v1.w};

        float mn = vals[0], mx = vals[0];
#pragma unroll
        for (int i = 1; i < 8; ++i) {
            mn = fminf(mn, vals[i]);
            mx = fmaxf(mx, vals[i]);
        }
#pragma unroll
        for (int off = 32; off >= 1; off >>= 1) {
            mn = fminf(mn, __shfl_xor(mn, off));
            mx = fmaxf(mx, __shfl_xor(mx, off));
        }
        if ((t & 63) == 0) { smn[t >> 6] = mn; smx[t >> 6] = mx; }
        __syncthreads();
        mn = fminf(fminf(smn[0], smn[1]), fminf(smn[2], smn[3]));
        mx = fmaxf(fmaxf(smx[0], smx[1]), fmaxf(smx[2], smx[3]));

        const float l = lws[row];
        const float ws = exp2f(l);     // power of two -> exact
        const float rs = exp2f(-l);    // exact reciprocal
        const float qwmin = rintf(mn * rs * 2.0f) * 0.5f * ws;  // WGT_GUARD=2
        const float qwmax = rintf(mx * rs * 2.0f) * 0.5f * ws;

        f16x8 out;
#pragma unroll
        for (int i = 0; i < 8; ++i) {
            float c = fminf(fmaxf(vals[i], qwmin), qwmax);
            float qw = rintf((c - qwmin) * rs);
            out[i] = (_Float16)(qw * ws + qwmin);
        }
        *(f16x8*)&Wq[(size_t)row * K + (size_t)t * 8] = out;
    }
}

// ---------------- GEMM: C[M][N] = A[M][K] * B[N][K]^T + bias ----------------
// == R5 (verified 265us) with new block mapping only ==
// Ledger (stage order per iteration i, tiles a=2i[db0], b=2i+1[db1],
// aN=a+2, bN=b+2):
//   P1: b.A0   P2: b.A1   P3: aN.B0   P4: aN.A0  | vmcnt(4)
//   P5: aN.A1  P6: aN.B1  P7: bN.B0   P8: bN.B1  | vmcnt(4)
// WAR: every slot's last ds_read completes >=1 barrier before its overwrite.
// Landing: vmcnt(4)@P4 => b.A0/A1 landed before P5; vmcnt(4)@P8 => aN.* landed
// before next-P1.
__global__ __launch_bounds__(512, 2) void gemm_kernel(
    const _Float16* __restrict__ A, const _Float16* __restrict__ B,
    const float* __restrict__ bias, float* __restrict__ C) {
    constexpr int N = 8192, K = 2048;
    constexpr int KT = K / 64;          // 32 K-tiles, 16 iterations

    __shared__ char smem[131072];       // A: 0..64K, B: 64K..128K

    // L2/L3-aware mapping: XCD x (= bid&7, dispatch round-robin) owns the
    // A-band bm in [4x, 4x+4) (4MB, fits its L2); j=bid>>3 walks bm fastest
    // so all XCDs sweep bn in lockstep -> B panels fetched from HBM once
    // chip-wide and served via L3. Bijective: (x,j) <-> (bm,bn).
    const int bid = blockIdx.x;
    const int j = bid >> 3;
    const int bm = (bid & 7) * 4 + (j & 3);
    const int bn = j >> 2;

    const int t = threadIdx.x;
    const int lane = t & 63;
    const int wid = t >> 6;
    const int wr = wid >> 2;            // 0..1 (M half)
    const int wc = wid & 3;             // 0..3 (N quarter)
    const int l15 = lane & 15;
    const int lq = lane >> 4;

    // staging: half-tile [128 rows][64 k] f16 = 16384 B, linear LDS dest,
    // pre-swizzled global source. T2 swizzle: byte ^= (row&7)<<4.
    const int d0 = t * 16, d1 = d0 + 8192;
    const int r0 = d0 >> 7, c0 = (((d0 & 127) ^ (((d0 >> 7) & 7) << 4)) >> 1);
    const int r1 = d1 >> 7, c1 = (((d1 & 127) ^ (((d1 >> 7) & 7) << 4)) >> 1);
    const _Float16* Agb = A + (size_t)bm * 256 * K;
    const _Float16* Bgb = B + (size_t)bn * 256 * K;

    // read-side swizzled k-col byte offsets (frag row&7 == l15&7)
    const int cp0 = (lq * 16) ^ ((l15 & 7) << 4);
    const int cp1 = cp0 ^ 64;           // second K-half: XOR, not add (bit6)

    f32x4 acc[8][4] = {};
    f16x8 fA0[4][2], fA1[4][2], fB0[2][2], fB1[2][2];

#define STAGE(GB, RO, DBS, H, KS) do {                                         \
        const _Float16* _g = (GB) + (size_t)((H) * 128) * K + (size_t)(KS) * 64;\
        char* _l = smem + (RO) + ((DBS) * 2 + (H)) * 16384;                    \
        gload_lds16(_g + (size_t)r0 * K + c0, _l + d0);                        \
        gload_lds16(_g + (size_t)r1 * K + c1, _l + d1);                        \
    } while (0)

#define LDAF(dst, DBv, MLO) do {                                               \
        const char* _s = smem + ((DBv) * 2 + wr) * 16384 + l15 * 128;          \
        _Pragma("unroll")                                                      \
        for (int _m = 0; _m < 4; ++_m) {                                       \
            dst[_m][0] = *(const f16x8*)(_s + ((MLO) + _m) * 2048 + cp0);      \
            dst[_m][1] = *(const f16x8*)(_s + ((MLO) + _m) * 2048 + cp1);      \
        }                                                                      \
    } while (0)

#define LDBF(dst, DBv, NLO) do {                                               \
        const char* _s = smem + 65536 + ((DBv) * 2 + (wc >> 1)) * 16384 +      \
                         (wc & 1) * 8192 + l15 * 128;                          \
        _Pragma("unroll")                                                      \
        for (int _n = 0; _n < 2; ++_n) {                                       \
            dst[_n][0] = *(const f16x8*)(_s + ((NLO) + _n) * 2048 + cp0);      \
            dst[_n][1] = *(const f16x8*)(_s + ((NLO) + _n) * 2048 + cp1);      \
        }                                                                      \
    } while (0)

#define QMFMA(MLO, NLO, AF, BF) do {                                           \
        _Pragma("unroll")                                                      \
        for (int _m = 0; _m < 4; ++_m)                                         \
            _Pragma("unroll")                                                  \
            for (int _n = 0; _n < 2; ++_n) {                                   \
                f32x4 _c = acc[(MLO) + _m][(NLO) + _n];                        \
                _c = __builtin_amdgcn_mfma_f32_16x16x32_f16(                   \
                    AF[_m][0], BF[_n][0], _c, 0, 0, 0);                        \
                _c = __builtin_amdgcn_mfma_f32_16x16x32_f16(                   \
                    AF[_m][1], BF[_n][1], _c, 0, 0, 0);                        \
                acc[(MLO) + _m][(NLO) + _n] = _c;                              \
            }                                                                  \
    } while (0)

// one K-tile = 4 phases. Quadrant order: (m0,n0)r12, (m0,n1)r4, (m1,n1)r8, (m1,n0)r0.
#define HALFITER(DBv, S1, S2, S3, S4, VMW) do {                                \
        /* P1: 12 ds_reads */                                                  \
        LDAF(fA0, DBv, 0); LDBF(fB0, DBv, 0);                                  \
        S1;                                                                    \
        asm volatile("s_waitcnt lgkmcnt(8)" ::: "memory");                     \
        __builtin_amdgcn_s_barrier();                                          \
        asm volatile("s_waitcnt lgkmcnt(0)" ::: "memory");                     \
        __builtin_amdgcn_s_setprio(1);                                         \
        QMFMA(0, 0, fA0, fB0);                                                 \
        __builtin_amdgcn_s_setprio(0);                                         \
        __builtin_amdgcn_s_barrier();                                          \
        /* P2: 4 ds_reads */                                                   \
        LDBF(fB1, DBv, 2);                                                     \
        S2;                                                                    \
        __builtin_amdgcn_s_barrier();                                          \
        asm volatile("s_waitcnt lgkmcnt(0)" ::: "memory");                     \
        __builtin_amdgcn_s_setprio(1);                                         \
        QMFMA(0, 2, fA0, fB1);                                                 \
        __builtin_amdgcn_s_setprio(0);                                         \
        __builtin_amdgcn_s_barrier();                                          \
        /* P3: 8 ds_reads */                                                   \
        LDAF(fA1, DBv, 4);                                                     \
        S3;                                                                    \
        __builtin_amdgcn_s_barrier();                                          \
        asm volatile("s_waitcnt lgkmcnt(0)" ::: "memory");                     \
        __builtin_amdgcn_s_setprio(1);                                         \
        QMFMA(4, 2, fA1, fB1);                                                 \
        __builtin_amdgcn_s_setprio(0);                                         \
        __builtin_amdgcn_s_barrier();                                          \
        /* P4: 0 ds_reads */                                                   \
        S4;                                                                    \
        __builtin_amdgcn_s_barrier();                                          \
        __builtin_amdgcn_s_setprio(1);                                         \
        QMFMA(4, 0, fA1, fB0);                                                 \
        __builtin_amdgcn_s_setprio(0);                                         \
        asm volatile("s_waitcnt vmcnt(" #VMW ")" ::: "memory");                \
        __builtin_amdgcn_s_barrier();                                          \
    } while (0)

    // ---- prologue: stage t0 all + t1.B0/B1; wait t0 landed ----
    STAGE(Bgb, 65536, 0, 0, 0);   // t0.B0
    STAGE(Agb, 0,     0, 0, 0);   // t0.A0
    STAGE(Agb, 0,     0, 1, 0);   // t0.A1
    STAGE(Bgb, 65536, 0, 1, 0);   // t0.B1
    STAGE(Bgb, 65536, 1, 0, 1);   // t1.B0
    STAGE(Bgb, 65536, 1, 1, 1);   // t1.B1
    asm volatile("s_waitcnt vmcnt(4)" ::: "memory");
    __builtin_amdgcn_s_barrier();

    for (int it = 0; it < KT / 2; ++it) {
        const int b  = 2 * it + 1;
        const int aN = (2 * it + 2 < KT) ? 2 * it + 2 : KT - 2;
        const int bN = (2 * it + 3 < KT) ? 2 * it + 3 : KT - 1;

        // tile a (db0): stages P1..P4 = b.A0, b.A1, aN.B0, aN.A0
        HALFITER(0,
                 STAGE(Agb, 0,     1, 0, b),
                 STAGE(Agb, 0,     1, 1, b),
                 STAGE(Bgb, 65536, 0, 0, aN),
                 STAGE(Agb, 0,     0, 0, aN), 4);
        // tile b (db1): stages P5..P8 = aN.A1, aN.B1, bN.B0, bN.B1
        HALFITER(1,
                 STAGE(Agb, 0,     0, 1, aN),
                 STAGE(Bgb, 65536, 0, 1, aN),
                 STAGE(Bgb, 65536, 1, 0, bN),
                 STAGE(Bgb, 65536, 1, 1, bN), 4);
    }
#undef HALFITER
#undef QMFMA
#undef LDBF
#undef LDAF
#undef STAGE

    // ---- epilogue: C/D mapping col=lane&15, row=(lane>>4)*4+reg ----
#pragma unroll
    for (int m = 0; m < 8; ++m) {
        const int row = bm * 256 + wr * 128 + m * 16 + lq * 4;
#pragma unroll
        for (int n = 0; n < 4; ++n) {
            const int col = bn * 256 + wc * 64 + n * 16 + l15;
            const float bv = bias[col];
#pragma unroll
            for (int r = 0; r < 4; ++r) {
                C[(size_t)(row + r) * N + col] = acc[m][n][r] + bv;
            }
        }
    }
}

extern "C" void kernel_launch(void* const* d_in, const int* in_sizes, int n_in,
                              void* d_out, int out_size, void* d_ws, size_t ws_size,
                              hipStream_t stream) {
    const float* x    = (const float*)d_in[0];   // [4,2048,2048]
    const float* w    = (const float*)d_in[1];   // [8192,2048]
    const float* bias = (const float*)d_in[2];   // [8192]
    const float* las  = (const float*)d_in[3];   // log_act_s [1]
    const float* laq  = (const float*)d_in[4];   // log_act_q [1]
    const float* ab   = (const float*)d_in[5];   // act_b [1]
    const float* lws  = (const float*)d_in[6];   // log_wght_s [8192]
    float* out = (float*)d_out;

    constexpr size_t MK = (size_t)8192 * 2048;
    _Float16* xq = (_Float16*)d_ws;
    _Float16* wq = (_Float16*)((char*)d_ws + MK * sizeof(_Float16));

    quant_kernel<<<16384, 256, 0, stream>>>(x, las, laq, ab, w, lws, xq, wq);
    gemm_kernel<<<1024, 512, 0, stream>>>(xq, wq, bias, out);
}